// Round 12
// baseline (237.260 us; speedup 1.0000x reference)
//
#include <hip/hip_runtime.h>
#include <hip/hip_bf16.h>

#define N_TOK 343
#define N_PAD 344
#define J_PAD 352
#define C_DIM 96
#define H_HEADS 24
#define HD 4
#define B_WIN 32
#define LOG2E 1.4426950408889634f
#define SCALE_Q (0.5f * LOG2E)    // attn scale folded with log2(e) for exp2-space softmax
#define EPS_IN 1e-5f
#define CH_STR (HD * N_PAD)                    // 1376 floats per (b,h)
#define AP ((size_t)B_WIN * H_HEADS * CH_STR)  // 1,056,768 floats per slot
#define BT_ELEMS ((size_t)H_HEADS * N_PAD * N_PAD)     // 2,840,064 floats (11.4 MB)
// layout of q/k/v/vf slots: [b][h][n][d] (float4 per token n), token row 343 = zero pad
// ws slots: 0=q1 1=k1 2=q2 3=k2 4=v1(->AO) 5=v2 6=vf [7: biasT if ws_size allows]

typedef float v2f __attribute__((ext_vector_type(2)));
#define FMA2(a, b, c) __builtin_elementwise_fma(a, b, c)
#define SBAR() __builtin_amdgcn_sched_barrier(0)

// ---------------- kernel 0: transposed bias: bT[h][j][i] = rpb[rel[i,j]*H+h]*log2e ----------------
__global__ __launch_bounds__(256) void biasT_kernel(const float* __restrict__ rpb,
                                                    const int* __restrict__ rel,
                                                    float* __restrict__ bT) {
    const int h = blockIdx.y;
    const int ti = blockIdx.x / 11, tj = blockIdx.x - 11 * (blockIdx.x / 11);
    const int i0 = ti * 32, j0 = tj * 32;
    __shared__ float tile[32][33];
    const int tid = threadIdx.x;
    for (int e = tid; e < 1024; e += 256) {
        int r = e >> 5, c = e & 31;            // r=i-local, c=j-local (coalesced over j)
        int i = i0 + r, j = j0 + c;
        float v = -16384.f;
        if (i < N_TOK && j < N_TOK) v = rpb[rel[i * N_TOK + j] * H_HEADS + h] * LOG2E;
        tile[r][c] = v;
    }
    __syncthreads();
    for (int e = tid; e < 1024; e += 256) {
        int c = e >> 5, r = e & 31;            // writes coalesced over i
        int i = i0 + r, j = j0 + c;
        if (i < N_PAD && j < N_PAD)
            bT[((size_t)h * N_PAD + j) * N_PAD + i] = tile[r][c];
    }
}

// ---------------- kernel 1: QKV projection, LDS-tiled GEMM ----------------
__global__ __launch_bounds__(192) void qkv_kernel(const float* __restrict__ x1,
                                                  const float* __restrict__ x2,
                                                  const float* __restrict__ w,
                                                  const float* __restrict__ bqkv,
                                                  float* __restrict__ ws) {
    __shared__ float wt[96 * 100];
    __shared__ float xs[2][32 * 97];
    const int s = blockIdx.y, b = blockIdx.z, r0 = blockIdx.x * 32;
    const int rows = min(32, N_TOK - r0);
    const int tid = threadIdx.x;
    for (int e = tid; e < 96 * 96; e += 192) {
        int j = e / 96, k = e - j * 96;
        wt[k * 100 + j] = w[s * 96 * 96 + e];
    }
    const float* x1p = x1 + ((size_t)b * N_TOK + r0) * C_DIM;
    const float* x2p = x2 + ((size_t)b * N_TOK + r0) * C_DIM;
    for (int e = tid; e < rows * 96; e += 192) {
        int r = e / 96, k = e - r * 96;
        xs[0][r * 97 + k] = x1p[e];
        xs[1][r * 97 + k] = x2p[e];
    }
    __syncthreads();
    const int rg = tid & 7, og = tid >> 3;   // og = head (0..23), rg = row group (0..7)
    const int oc0 = og * 4, rr = rg * 4;
    float acc[2][4][4];
    #pragma unroll
    for (int i = 0; i < 4; ++i) {
        float bv = bqkv[s * 96 + oc0 + i];
        #pragma unroll
        for (int src = 0; src < 2; ++src)
            #pragma unroll
            for (int j = 0; j < 4; ++j) acc[src][i][j] = bv;
    }
    for (int k = 0; k < 96; ++k) {
        float4 w4 = *(const float4*)&wt[k * 100 + oc0];
        float wv[4] = {w4.x, w4.y, w4.z, w4.w};
        float xv0[4], xv1[4];
        #pragma unroll
        for (int j = 0; j < 4; ++j) {
            xv0[j] = xs[0][(rr + j) * 97 + k];
            xv1[j] = xs[1][(rr + j) * 97 + k];
        }
        #pragma unroll
        for (int i = 0; i < 4; ++i)
            #pragma unroll
            for (int j = 0; j < 4; ++j) {
                acc[0][i][j] += xv0[j] * wv[i];
                acc[1][i][j] += xv1[j] * wv[i];
            }
    }
    const float scl = (s == 0) ? SCALE_Q : 1.0f;
    // store layout: [b][h=og][row][d]; row 343 (=N_TOK) is the pad row -> zeros
    #pragma unroll
    for (int j = 0; j < 4; ++j) {
        int row = r0 + rr + j;
        if (row > N_TOK) continue;
        size_t base = (((size_t)b * H_HEADS + og) * N_PAD + row) * 4;
        #pragma unroll
        for (int src = 0; src < 2; ++src) {
            int slot = (s == 0) ? (src ? 2 : 0) : (s == 1) ? (src ? 3 : 1) : (src ? 5 : 4);
            float4 val = (row == N_TOK)
                ? make_float4(0.f, 0.f, 0.f, 0.f)
                : make_float4(acc[src][0][j] * scl, acc[src][1][j] * scl,
                              acc[src][2][j] * scl, acc[src][3][j] * scl);
            *(float4*)(ws + (size_t)slot * AP + base) = val;
        }
    }
}

// ---------------- kernel 2: fuse (1x1 conv 48->24 + InstanceNorm + relu + sigmoid) ----------------
__global__ __launch_bounds__(256) void fuse_kernel(const float* __restrict__ v1,
                                                   const float* __restrict__ v2,
                                                   const float* __restrict__ fw,
                                                   const float* __restrict__ fb,
                                                   float* __restrict__ vf) {
    const int o = blockIdx.x, b = blockIdx.y;
    __shared__ float ts[N_TOK * HD];
    __shared__ float red[32];
    __shared__ float fwl[48];
    if (threadIdx.x < 48) fwl[threadIdx.x] = fw[o * 48 + threadIdx.x];
    __syncthreads();
    const float bo = fb[o];
    const float* p1 = v1 + (size_t)b * H_HEADS * CH_STR;
    const float* p2 = v2 + (size_t)b * H_HEADS * CH_STR;
    float lsum = 0.f, lsq = 0.f;
    for (int e = threadIdx.x; e < N_TOK * HD; e += blockDim.x) {
        float acc = bo;                        // e = n*4+d matches [n][d] layout directly
        #pragma unroll
        for (int c = 0; c < H_HEADS; ++c) {
            acc += fwl[c]      * p1[(size_t)c * CH_STR + e];
            acc += fwl[24 + c] * p2[(size_t)c * CH_STR + e];
        }
        ts[e] = acc;
        lsum += acc; lsq += acc * acc;
    }
    for (int off = 32; off; off >>= 1) {
        lsum += __shfl_xor(lsum, off);
        lsq  += __shfl_xor(lsq, off);
    }
    int wid = threadIdx.x >> 6, lane = threadIdx.x & 63;
    if (lane == 0) { red[wid] = lsum; red[8 + wid] = lsq; }
    __syncthreads();
    if (threadIdx.x == 0) {
        float su = red[0] + red[1] + red[2] + red[3];
        float q  = red[8] + red[9] + red[10] + red[11];
        float mean = su / (float)(N_TOK * HD);
        float var  = q / (float)(N_TOK * HD) - mean * mean;
        red[16] = mean;
        red[17] = rsqrtf(var + EPS_IN);
    }
    __syncthreads();
    const float mean = red[16], inv = red[17];
    float* outp = vf + ((size_t)b * H_HEADS + o) * CH_STR;
    for (int e = threadIdx.x; e < N_TOK * HD; e += blockDim.x) {
        float x = (ts[e] - mean) * inv;
        x = fmaxf(x, 0.f);
        outp[e] = 1.f / (1.f + __expf(-x));
    }
}

// ---------------- kernel 3: attention v6 — pipelined with sched_barrier fences ----------------
// block (h,b), 192 threads, lanes 0..171 own row pair (2l, 2l+1).
// 344 = 43 x 8 j's; two named batches; sched_barrier(0) pins loads a full
// compute-phase ahead (compiler cannot re-sink them); running pointers.
struct JBatch {
    v2f bv[4];
    float4 k1[4], k2[4], vv[4];
};

#define LOAD_BATCH_P(B_, PB_, PK1_, PK2_, PV_)                         \
    _Pragma("unroll")                                                  \
    for (int u = 0; u < 4; ++u) {                                      \
        B_.bv[u] = *(const v2f*)(PB_ + (size_t)u * N_PAD);             \
        B_.k1[u] = (PK1_)[u];                                          \
        B_.k2[u] = (PK2_)[u];                                          \
        B_.vv[u] = (PV_)[u];                                           \
    }

#define COMP_BATCH(B_)                                                 \
    _Pragma("unroll")                                                  \
    for (int u = 0; u < 4; ++u) {                                      \
        const float4 k1 = B_.k1[u], k2 = B_.k2[u], v = B_.vv[u];       \
        v2f s2 = B_.bv[u];                                             \
        s2 = FMA2((v2f)(k1.x), q1p0, s2); s2 = FMA2((v2f)(k1.y), q1p1, s2); \
        s2 = FMA2((v2f)(k1.z), q1p2, s2); s2 = FMA2((v2f)(k1.w), q1p3, s2); \
        s2 = FMA2((v2f)(k2.x), q2p0, s2); s2 = FMA2((v2f)(k2.y), q2p1, s2); \
        s2 = FMA2((v2f)(k2.z), q2p2, s2); s2 = FMA2((v2f)(k2.w), q2p3, s2); \
        const v2f p2 = {exp2f(s2.x), exp2f(s2.y)};                     \
        sum2 += p2;                                                    \
        a0 = FMA2(p2, (v2f)(v.x), a0); a1 = FMA2(p2, (v2f)(v.y), a1);  \
        a2 = FMA2(p2, (v2f)(v.z), a2); a3 = FMA2(p2, (v2f)(v.w), a3);  \
    }

__global__ __launch_bounds__(192) void attn_kernel(const float* __restrict__ ws,
                                                   const float* __restrict__ bT,
                                                   const float* __restrict__ vf,
                                                   float* __restrict__ ao) {
    const int h = blockIdx.x, b = blockIdx.y;
    const int l = threadIdx.x;
    if (l >= 172) return;                      // no barriers in kernel -> early exit safe
    const size_t off = ((size_t)b * H_HEADS + h) * CH_STR;
    const float4* __restrict__ K1 = (const float4*)(ws + 1 * AP + off);
    const float4* __restrict__ K2 = (const float4*)(ws + 3 * AP + off);
    const float4* __restrict__ Vv = (const float4*)(vf + off);
    const float*  __restrict__ Q1 = ws + 0 * AP + off;
    const float*  __restrict__ Q2 = ws + 2 * AP + off;
    const int rA = l * 2, rB = rA + 1;         // rB == 343 only at l=171 (pad row, q=0)
    const float4 q1a = *(const float4*)&Q1[rA * 4];
    const float4 q1b = *(const float4*)&Q1[rB * 4];
    const float4 q2a = *(const float4*)&Q2[rA * 4];
    const float4 q2b = *(const float4*)&Q2[rB * 4];
    const v2f q1p0 = {q1a.x, q1b.x}, q1p1 = {q1a.y, q1b.y},
              q1p2 = {q1a.z, q1b.z}, q1p3 = {q1a.w, q1b.w};
    const v2f q2p0 = {q2a.x, q2b.x}, q2p1 = {q2a.y, q2b.y},
              q2p2 = {q2a.z, q2b.z}, q2p3 = {q2a.w, q2b.w};
    v2f sum2 = {0.f, 0.f};
    v2f a0 = {0.f, 0.f}, a1 = {0.f, 0.f}, a2 = {0.f, 0.f}, a3 = {0.f, 0.f};

    // running pointers (strength-reduced: one += per batch)
    const float* bPA = bT + (size_t)h * N_PAD * N_PAD + rA;
    const float* bPB = bPA + 4 * N_PAD;
    const float4 *k1A = K1,     *k2A = K2,     *vA = Vv;
    const float4 *k1B = K1 + 4, *k2B = K2 + 4, *vB = Vv + 4;

    JBatch A, B;
    LOAD_BATCH_P(A, bPA, k1A, k2A, vA)
    bPA += 8 * N_PAD; k1A += 8; k2A += 8; vA += 8;
    SBAR();
    LOAD_BATCH_P(B, bPB, k1B, k2B, vB)
    bPB += 8 * N_PAD; k1B += 8; k2B += 8; vB += 8;
    SBAR();
    for (int t = 0; t < 43; ++t) {
        COMP_BATCH(A)
        SBAR();
        if (t < 42) {
            LOAD_BATCH_P(A, bPA, k1A, k2A, vA)
            bPA += 8 * N_PAD; k1A += 8; k2A += 8; vA += 8;
        }
        SBAR();
        COMP_BATCH(B)
        SBAR();
        if (t < 42) {
            LOAD_BATCH_P(B, bPB, k1B, k2B, vB)
            bPB += 8 * N_PAD; k1B += 8; k2B += 8; vB += 8;
        }
        SBAR();
    }
    {
        const float inv = 1.f / sum2.x;
        float* op = ao + ((size_t)b * N_TOK + rA) * C_DIM + h * HD;
        *(float4*)op = make_float4(a0.x * inv, a1.x * inv, a2.x * inv, a3.x * inv);
    }
    if (rB < N_TOK) {
        const float inv = 1.f / sum2.y;
        float* op = ao + ((size_t)b * N_TOK + rB) * C_DIM + h * HD;
        *(float4*)op = make_float4(a0.y * inv, a1.y * inv, a2.y * inv, a3.y * inv);
    }
}

// fallback variant: in-kernel gather (if ws too small for biasT slot), [n][d] layout
__global__ __launch_bounds__(256) void attn_kernel_g(const float* __restrict__ ws,
                                                     const float* __restrict__ rpb,
                                                     const int* __restrict__ rel,
                                                     const float* __restrict__ vf,
                                                     float* __restrict__ ao) {
    const int h = blockIdx.x, b = blockIdx.y;
    __shared__ float k1s[J_PAD * 4], k2s[J_PAD * 4], vs[J_PAD * 4];
    __shared__ float q1s[N_PAD * 4], q2s[N_PAD * 4];
    const size_t off = ((size_t)b * H_HEADS + h) * CH_STR;
    const float* Q1 = ws + 0 * AP + off;
    const float* K1 = ws + 1 * AP + off;
    const float* Q2 = ws + 2 * AP + off;
    const float* K2 = ws + 3 * AP + off;
    const float* V  = vf + off;
    const int tid = threadIdx.x;
    for (int e = tid; e < N_PAD * 4; e += 256) {
        k1s[e] = K1[e]; k2s[e] = K2[e]; vs[e] = V[e];
        q1s[e] = Q1[e]; q2s[e] = Q2[e];
    }
    for (int e = N_PAD * 4 + tid; e < J_PAD * 4; e += 256) {
        k1s[e] = 0.f; k2s[e] = 0.f; vs[e] = 0.f;
    }
    __syncthreads();
    const int wid = tid >> 6, lane = tid & 63;
    const int grp = lane >> 4, l16 = lane & 15;
    const float* rpbh = rpb + h;
    for (int t = 0; t < 22; ++t) {
        const int i = t * 16 + wid * 4 + grp;
        const int ig = min(i, N_TOK - 1);
        const float4 q1 = *(const float4*)&q1s[ig * 4];
        const float4 q2 = *(const float4*)&q2s[ig * 4];
        const int* relRow = rel + (size_t)ig * N_TOK;
        float sum = 0.f, a0 = 0.f, a1 = 0.f, a2 = 0.f, a3 = 0.f;
        #pragma unroll 4
        for (int it = 0; it < 22; ++it) {
            const int jj = it * 16 + l16;
            float s = (jj < N_TOK) ? rpbh[relRow[jj] * H_HEADS] * LOG2E : -16384.f;
            const float4 k1 = *(const float4*)&k1s[jj * 4];
            const float4 k2 = *(const float4*)&k2s[jj * 4];
            s = fmaf(q1.x, k1.x, s); s = fmaf(q1.y, k1.y, s);
            s = fmaf(q1.z, k1.z, s); s = fmaf(q1.w, k1.w, s);
            s = fmaf(q2.x, k2.x, s); s = fmaf(q2.y, k2.y, s);
            s = fmaf(q2.z, k2.z, s); s = fmaf(q2.w, k2.w, s);
            const float p = exp2f(s);
            const float4 v = *(const float4*)&vs[jj * 4];
            sum += p;
            a0 = fmaf(p, v.x, a0); a1 = fmaf(p, v.y, a1);
            a2 = fmaf(p, v.z, a2); a3 = fmaf(p, v.w, a3);
        }
        #pragma unroll
        for (int o = 8; o; o >>= 1) {
            sum += __shfl_xor(sum, o, 16);
            a0 += __shfl_xor(a0, o, 16); a1 += __shfl_xor(a1, o, 16);
            a2 += __shfl_xor(a2, o, 16); a3 += __shfl_xor(a3, o, 16);
        }
        if (l16 == 0 && i < N_TOK) {
            const float inv = 1.f / sum;
            float* op = ao + ((size_t)b * N_TOK + i) * C_DIM + h * HD;
            *(float4*)op = make_float4(a0 * inv, a1 * inv, a2 * inv, a3 * inv);
        }
    }
}

// ---------------- kernel 4: output projection (32-row tiles) -> float32 ----------------
__global__ __launch_bounds__(256) void proj_kernel(const float* __restrict__ ao,
                                                   const float* __restrict__ pw,
                                                   const float* __restrict__ pb,
                                                   float* __restrict__ out) {
    __shared__ float xs[32 * C_DIM];
    __shared__ float pwl[C_DIM * 97];
    const int b = blockIdx.y, row0 = blockIdx.x * 32;
    const int rows = min(32, N_TOK - row0);
    for (int e = threadIdx.x; e < rows * C_DIM; e += blockDim.x)
        xs[e] = ao[((size_t)b * N_TOK + row0) * C_DIM + e];
    for (int e = threadIdx.x; e < C_DIM * C_DIM; e += blockDim.x) {
        int c = e / C_DIM, k = e - c * C_DIM;
        pwl[c * 97 + k] = pw[e];
    }
    __syncthreads();
    for (int e = threadIdx.x; e < rows * C_DIM; e += blockDim.x) {
        int r = e / C_DIM, c = e - r * C_DIM;
        float acc = pb[c];
        const float* xr = xs + r * C_DIM;
        const float* wr = pwl + c * 97;
        #pragma unroll 8
        for (int k = 0; k < C_DIM; ++k) acc += xr[k] * wr[k];
        out[((size_t)b * N_TOK + row0) * C_DIM + e] = acc;
    }
}

static const void* find_by_size(void* const* d_in, const int* in_sizes, int n_in,
                                int want, int occurrence) {
    int seen = 0;
    for (int i = 0; i < n_in; ++i) {
        if (in_sizes[i] == want) {
            if (seen == occurrence) return d_in[i];
            ++seen;
        }
    }
    return nullptr;
}

extern "C" void kernel_launch(void* const* d_in, const int* in_sizes, int n_in,
                              void* d_out, int out_size, void* d_ws, size_t ws_size,
                              hipStream_t stream) {
    const float* x1     = (const float*)find_by_size(d_in, in_sizes, n_in, 1053696, 0);
    const float* x2     = (const float*)find_by_size(d_in, in_sizes, n_in, 1053696, 1);
    const float* qkv_w  = (const float*)find_by_size(d_in, in_sizes, n_in, 27648, 0);
    const float* qkv_b  = (const float*)find_by_size(d_in, in_sizes, n_in, 288, 0);
    const float* proj_w = (const float*)find_by_size(d_in, in_sizes, n_in, 9216, 0);
    const float* proj_b = (const float*)find_by_size(d_in, in_sizes, n_in, 96, 0);
    const float* rpb    = (const float*)find_by_size(d_in, in_sizes, n_in, 52728, 0);
    const float* fuse_w = (const float*)find_by_size(d_in, in_sizes, n_in, 1152, 0);
    const float* fuse_b = (const float*)find_by_size(d_in, in_sizes, n_in, 24, 0);
    const int*   rel    = (const int*)  find_by_size(d_in, in_sizes, n_in, 117649, 0);

    if (!x1 || !x2 || !qkv_w || !qkv_b || !proj_w || !proj_b || !rpb || !fuse_w ||
        !fuse_b || !rel) {
        x1     = (const float*)d_in[0];
        x2     = (const float*)d_in[1];
        qkv_w  = (const float*)d_in[2];
        qkv_b  = (const float*)d_in[3];
        proj_w = (const float*)d_in[4];
        proj_b = (const float*)d_in[5];
        rpb    = (const float*)d_in[6];
        fuse_w = (const float*)d_in[7];
        fuse_b = (const float*)d_in[8];
        rel    = (const int*)d_in[9];
    }

    float* ws = (float*)d_ws;
    float* V1 = ws + 4 * AP;
    float* V2 = ws + 5 * AP;
    float* VF = ws + 6 * AP;
    float* AO = V1;            // alias: v1 dead after fuse_kernel
    float* BIAS = ws + 7 * AP;
    float* out = (float*)d_out;
    const bool use_bias = ws_size >= (7 * AP + BT_ELEMS) * sizeof(float);

    if (use_bias)
        biasT_kernel<<<dim3(121, H_HEADS), 256, 0, stream>>>(rpb, rel, BIAS);
    qkv_kernel<<<dim3(11, 3, B_WIN), 192, 0, stream>>>(x1, x2, qkv_w, qkv_b, ws);
    fuse_kernel<<<dim3(H_HEADS, B_WIN), 256, 0, stream>>>(V1, V2, fuse_w, fuse_b, VF);
    if (use_bias)
        attn_kernel<<<dim3(H_HEADS, B_WIN), 192, 0, stream>>>(ws, BIAS, VF, AO);
    else
        attn_kernel_g<<<dim3(H_HEADS, B_WIN), 256, 0, stream>>>(ws, rpb, rel, VF, AO);
    proj_kernel<<<dim3(11, B_WIN), 256, 0, stream>>>(AO, proj_w, proj_b, out);
}

// Round 13
// 205.092 us; speedup vs baseline: 1.1568x; 1.1568x over previous
//
#include <hip/hip_runtime.h>
#include <hip/hip_bf16.h>

#define N_TOK 343
#define N_PAD 344
#define BT_J 352                  // bias j-extent (padded to 22 batches of 16)
#define C_DIM 96
#define H_HEADS 24
#define HD 4
#define B_WIN 32
#define LOG2E 1.4426950408889634f
#define SCALE_Q (0.5f * LOG2E)    // attn scale folded with log2(e) for exp2-space softmax
#define EPS_IN 1e-5f
#define CH_STR (HD * N_PAD)                    // 1376 floats per (b,h)
#define AP ((size_t)B_WIN * H_HEADS * CH_STR)  // 1,056,768 floats per slot
#define BT_ELEMS ((size_t)H_HEADS * BT_J * N_PAD)      // 2,906,112 floats (11.6 MB)
#define PS_HALF ((size_t)B_WIN * H_HEADS * N_PAD)      // 264,192 floats
// q/k/v/vf slots: [b][h][n][d] (float4 per token n), token row 343 = zero pad
// ws map (floats): [0..7AP) = q1,k1,q2,k2,v1(->AO),v2,vf | [7AP..+BT) = bT
//                  [.. +2AP) = Pa halves | [.. +2*PS_HALF) = Ps halves

typedef float v2f __attribute__((ext_vector_type(2)));
#define FMA2(a, b, c) __builtin_elementwise_fma(a, b, c)

// ---------------- kernel 1: prep = {QKV GEMM (src-split) | biasT gather} ----------------
// flattened grid: [0,2112) qkv, [2112,5016) biasT. 192 threads, 50.8 KB LDS shared.
__global__ __launch_bounds__(192) void prep_kernel(const float* __restrict__ x1,
                                                   const float* __restrict__ x2,
                                                   const float* __restrict__ w,
                                                   const float* __restrict__ bqkv,
                                                   const float* __restrict__ rpb,
                                                   const int* __restrict__ rel,
                                                   float* __restrict__ ws,
                                                   float* __restrict__ bT) {
    __shared__ float smem[12704];              // xs[0..3104) wt[3104..12704) | biasT tile
    const int bid = blockIdx.x, tid = threadIdx.x;
    if (bid < 2112) {
        // ---- qkv part: one (row-tile, s, src, b) ----
        const int r0t = bid % 11;
        const int rest = bid / 11;
        const int sy = rest % 6, b = rest / 6;
        const int s = sy >> 1, src = sy & 1;
        const int r0 = r0t * 32;
        const int rows = min(32, N_TOK - r0);
        float* xs = smem;                      // [32][97]
        float* wt = smem + 3104;               // [96][100]
        for (int e = tid; e < 96 * 96; e += 192) {
            int j = e / 96, k = e - j * 96;
            wt[k * 100 + j] = w[s * 96 * 96 + e];
        }
        const float* xp = (src == 0 ? x1 : x2) + ((size_t)b * N_TOK + r0) * C_DIM;
        for (int e = tid; e < rows * 96; e += 192) {
            int r = e / 96, k = e - r * 96;
            xs[r * 97 + k] = xp[e];
        }
        __syncthreads();
        const int rg = tid & 7, og = tid >> 3; // og = head (0..23), rg = row group (0..7)
        const int oc0 = og * 4, rr = rg * 4;
        float acc[4][4];
        #pragma unroll
        for (int i = 0; i < 4; ++i) {
            float bv = bqkv[s * 96 + oc0 + i];
            #pragma unroll
            for (int j = 0; j < 4; ++j) acc[i][j] = bv;
        }
        for (int k = 0; k < 96; ++k) {
            float4 w4 = *(const float4*)&wt[k * 100 + oc0];
            float wv[4] = {w4.x, w4.y, w4.z, w4.w};
            float xv[4];
            #pragma unroll
            for (int j = 0; j < 4; ++j) xv[j] = xs[(rr + j) * 97 + k];
            #pragma unroll
            for (int i = 0; i < 4; ++i)
                #pragma unroll
                for (int j = 0; j < 4; ++j) acc[i][j] += xv[j] * wv[i];
        }
        const float scl = (s == 0) ? SCALE_Q : 1.0f;
        const int slot = (s == 0) ? (src ? 2 : 0) : (s == 1) ? (src ? 3 : 1) : (src ? 5 : 4);
        #pragma unroll
        for (int j = 0; j < 4; ++j) {
            int row = r0 + rr + j;
            if (row > N_TOK) continue;         // row==343: zero pad row
            size_t base = (((size_t)b * H_HEADS + og) * N_PAD + row) * 4;
            float4 val = (row == N_TOK)
                ? make_float4(0.f, 0.f, 0.f, 0.f)
                : make_float4(acc[0][j] * scl, acc[1][j] * scl,
                              acc[2][j] * scl, acc[3][j] * scl);
            *(float4*)(ws + (size_t)slot * AP + base) = val;
        }
    } else {
        // ---- biasT part: bT[h][j][i] = rpb[rel[i,j]*H+h]*log2e, pads -16384 ----
        const int bid2 = bid - 2112;
        const int h = bid2 / 121;
        const int t = bid2 - h * 121;
        const int ti = t / 11, tj = t - ti * 11;
        const int i0 = ti * 32, j0 = tj * 32;
        float* tile = smem;                    // [32][33]
        for (int e = tid; e < 1024; e += 192) {
            int r = e >> 5, c = e & 31;        // r=i-local, c=j-local (coalesced over j)
            int i = i0 + r, j = j0 + c;
            float v = -16384.f;
            if (i < N_TOK && j < N_TOK) v = rpb[rel[i * N_TOK + j] * H_HEADS + h] * LOG2E;
            tile[r * 33 + c] = v;
        }
        __syncthreads();
        for (int e = tid; e < 1024; e += 192) {
            int c = e >> 5, r = e & 31;        // writes coalesced over i
            int i = i0 + r, j = j0 + c;
            if (i < N_PAD)                     // j < 352 always
                bT[((size_t)h * BT_J + j) * N_PAD + i] = tile[r * 33 + c];
        }
    }
}

// ---------------- kernel 2: fuse (1x1 conv 48->24 + InstanceNorm + relu + sigmoid) ----------------
__global__ __launch_bounds__(256) void fuse_kernel(const float* __restrict__ v1,
                                                   const float* __restrict__ v2,
                                                   const float* __restrict__ fw,
                                                   const float* __restrict__ fb,
                                                   float* __restrict__ vf) {
    const int o = blockIdx.x, b = blockIdx.y;
    __shared__ float ts[N_TOK * HD];
    __shared__ float red[32];
    __shared__ float fwl[48];
    if (threadIdx.x < 48) fwl[threadIdx.x] = fw[o * 48 + threadIdx.x];
    __syncthreads();
    const float bo = fb[o];
    const float* p1 = v1 + (size_t)b * H_HEADS * CH_STR;
    const float* p2 = v2 + (size_t)b * H_HEADS * CH_STR;
    float lsum = 0.f, lsq = 0.f;
    for (int e = threadIdx.x; e < N_TOK * HD; e += blockDim.x) {
        float acc = bo;
        #pragma unroll
        for (int c = 0; c < H_HEADS; ++c) {
            acc += fwl[c]      * p1[(size_t)c * CH_STR + e];
            acc += fwl[24 + c] * p2[(size_t)c * CH_STR + e];
        }
        ts[e] = acc;
        lsum += acc; lsq += acc * acc;
    }
    for (int off = 32; off; off >>= 1) {
        lsum += __shfl_xor(lsum, off);
        lsq  += __shfl_xor(lsq, off);
    }
    int wid = threadIdx.x >> 6, lane = threadIdx.x & 63;
    if (lane == 0) { red[wid] = lsum; red[8 + wid] = lsq; }
    __syncthreads();
    if (threadIdx.x == 0) {
        float su = red[0] + red[1] + red[2] + red[3];
        float q  = red[8] + red[9] + red[10] + red[11];
        float mean = su / (float)(N_TOK * HD);
        float var  = q / (float)(N_TOK * HD) - mean * mean;
        red[16] = mean;
        red[17] = rsqrtf(var + EPS_IN);
    }
    __syncthreads();
    const float mean = red[16], inv = red[17];
    float* outp = vf + ((size_t)b * H_HEADS + o) * CH_STR;
    for (int e = threadIdx.x; e < N_TOK * HD; e += blockDim.x) {
        float x = (ts[e] - mean) * inv;
        x = fmaxf(x, 0.f);
        outp[e] = 1.f / (1.f + __expf(-x));
    }
}

// ---------------- attention: shared pieces ----------------
struct JBatch {
    v2f bv[4];
    float4 k1[4], k2[4], vv[4];
};

#define LOAD_BATCH(B_, j0_)                                            \
    _Pragma("unroll")                                                  \
    for (int u = 0; u < 4; ++u) {                                      \
        B_.bv[u] = *(const v2f*)(bP + (size_t)((j0_) + u) * N_PAD);    \
        B_.k1[u] = K1[(j0_) + u];                                      \
        B_.k2[u] = K2[(j0_) + u];                                      \
        B_.vv[u] = Vv[(j0_) + u];                                      \
    }

#define COMP_BATCH(B_)                                                 \
    _Pragma("unroll")                                                  \
    for (int u = 0; u < 4; ++u) {                                      \
        const float4 k1 = B_.k1[u], k2 = B_.k2[u], v = B_.vv[u];       \
        v2f s2 = B_.bv[u];                                             \
        s2 = FMA2((v2f)(k1.x), q1p0, s2); s2 = FMA2((v2f)(k1.y), q1p1, s2); \
        s2 = FMA2((v2f)(k1.z), q1p2, s2); s2 = FMA2((v2f)(k1.w), q1p3, s2); \
        s2 = FMA2((v2f)(k2.x), q2p0, s2); s2 = FMA2((v2f)(k2.y), q2p1, s2); \
        s2 = FMA2((v2f)(k2.z), q2p2, s2); s2 = FMA2((v2f)(k2.w), q2p3, s2); \
        const v2f p2 = {exp2f(s2.x), exp2f(s2.y)};                     \
        sum2 += p2;                                                    \
        a0 = FMA2(p2, (v2f)(v.x), a0); a1 = FMA2(p2, (v2f)(v.y), a1);  \
        a2 = FMA2(p2, (v2f)(v.z), a2); a3 = FMA2(p2, (v2f)(v.w), a3);  \
    }

#define ATTN_SETUP                                                                 \
    const size_t off = ((size_t)b * H_HEADS + h) * CH_STR;                         \
    const float4* __restrict__ K1 = (const float4*)(ws + 1 * AP + off);            \
    const float4* __restrict__ K2 = (const float4*)(ws + 3 * AP + off);            \
    const float4* __restrict__ Vv = (const float4*)(vf + off);                     \
    const float*  __restrict__ Q1 = ws + 0 * AP + off;                             \
    const float*  __restrict__ Q2 = ws + 2 * AP + off;                             \
    const int rA = l * 2, rB = rA + 1;                                             \
    const float4 q1a = *(const float4*)&Q1[rA * 4];                                \
    const float4 q1b = *(const float4*)&Q1[rB * 4];                                \
    const float4 q2a = *(const float4*)&Q2[rA * 4];                                \
    const float4 q2b = *(const float4*)&Q2[rB * 4];                                \
    const v2f q1p0 = {q1a.x, q1b.x}, q1p1 = {q1a.y, q1b.y},                        \
              q1p2 = {q1a.z, q1b.z}, q1p3 = {q1a.w, q1b.w};                        \
    const v2f q2p0 = {q2a.x, q2b.x}, q2p1 = {q2a.y, q2b.y},                        \
              q2p2 = {q2a.z, q2b.z}, q2p3 = {q2a.w, q2b.w};                        \
    v2f sum2 = {0.f, 0.f};                                                         \
    v2f a0 = {0.f, 0.f}, a1 = {0.f, 0.f}, a2 = {0.f, 0.f}, a3 = {0.f, 0.f};

// ---------------- kernel 3a: attention halves -> additive partials ----------------
// grid (h, b, half); half j-ranges [0,176) and [176,352); pad j's contribute 0.
__global__ __launch_bounds__(192) void attn_part(const float* __restrict__ ws,
                                                 const float* __restrict__ bT,
                                                 const float* __restrict__ vf,
                                                 float* __restrict__ Pa,
                                                 float* __restrict__ Ps) {
    const int h = blockIdx.x, b = blockIdx.y, half = blockIdx.z;
    const int l = threadIdx.x;
    if (l >= 172) return;
    ATTN_SETUP
    const int j0h = half * 176;
    const float* bP = bT + ((size_t)h * BT_J + j0h) * N_PAD + rA;
    K1 += j0h; K2 += j0h; Vv += j0h;           // overreads past 343 are finite; bias kills them
    JBatch A, B;
    LOAD_BATCH(A, 0)
    LOAD_BATCH(B, 4)
    for (int t = 0; t < 22; ++t) {
        const int jb = t * 8;
        COMP_BATCH(A)
        if (t < 21) { LOAD_BATCH(A, jb + 8) }
        COMP_BATCH(B)
        if (t < 21) { LOAD_BATCH(B, jb + 12) }
    }
    float* PaH = Pa + (size_t)half * AP;
    float* PsH = Ps + (size_t)half * PS_HALF;
    const size_t pi = ((size_t)b * H_HEADS + h) * N_PAD;
    *(float4*)(PaH + (pi + rA) * 4) = make_float4(a0.x, a1.x, a2.x, a3.x);
    *(float4*)(PaH + (pi + rB) * 4) = make_float4(a0.y, a1.y, a2.y, a3.y);
    PsH[pi + rA] = sum2.x;
    PsH[pi + rB] = sum2.y;                     // rB==343 lands in pad slot
}

// ---------------- kernel 3b: full-j attention (fallback when ws lacks partial space) ----------------
__global__ __launch_bounds__(192) void attn_full(const float* __restrict__ ws,
                                                 const float* __restrict__ bT,
                                                 const float* __restrict__ vf,
                                                 float* __restrict__ ao) {
    const int h = blockIdx.x, b = blockIdx.y;
    const int l = threadIdx.x;
    if (l >= 172) return;
    ATTN_SETUP
    const float* bP = bT + (size_t)h * BT_J * N_PAD + rA;
    JBatch A, B;
    LOAD_BATCH(A, 0)
    LOAD_BATCH(B, 4)
    for (int t = 0; t < 43; ++t) {
        const int jb = t * 8;
        COMP_BATCH(A)
        if (t < 42) { LOAD_BATCH(A, jb + 8) }
        COMP_BATCH(B)
        if (t < 42) { LOAD_BATCH(B, jb + 12) }
    }
    {
        const float inv = 1.f / sum2.x;
        float* op = ao + ((size_t)b * N_TOK + rA) * C_DIM + h * HD;
        *(float4*)op = make_float4(a0.x * inv, a1.x * inv, a2.x * inv, a3.x * inv);
    }
    if (rB < N_TOK) {
        const float inv = 1.f / sum2.y;
        float* op = ao + ((size_t)b * N_TOK + rB) * C_DIM + h * HD;
        *(float4*)op = make_float4(a0.y * inv, a1.y * inv, a2.y * inv, a3.y * inv);
    }
}

// ---------------- kernel 3c: in-kernel gather fallback (no bias table at all) ----------------
__global__ __launch_bounds__(256) void attn_kernel_g(const float* __restrict__ ws,
                                                     const float* __restrict__ rpb,
                                                     const int* __restrict__ rel,
                                                     const float* __restrict__ vf,
                                                     float* __restrict__ ao) {
    const int h = blockIdx.x, b = blockIdx.y;
    __shared__ float k1s[BT_J * 4], k2s[BT_J * 4], vs[BT_J * 4];
    __shared__ float q1s[N_PAD * 4], q2s[N_PAD * 4];
    const size_t off = ((size_t)b * H_HEADS + h) * CH_STR;
    const float* Q1 = ws + 0 * AP + off;
    const float* K1 = ws + 1 * AP + off;
    const float* Q2 = ws + 2 * AP + off;
    const float* K2 = ws + 3 * AP + off;
    const float* V  = vf + off;
    const int tid = threadIdx.x;
    for (int e = tid; e < N_PAD * 4; e += 256) {
        k1s[e] = K1[e]; k2s[e] = K2[e]; vs[e] = V[e];
        q1s[e] = Q1[e]; q2s[e] = Q2[e];
    }
    for (int e = N_PAD * 4 + tid; e < BT_J * 4; e += 256) {
        k1s[e] = 0.f; k2s[e] = 0.f; vs[e] = 0.f;
    }
    __syncthreads();
    const int wid = tid >> 6, lane = tid & 63;
    const int grp = lane >> 4, l16 = lane & 15;
    const float* rpbh = rpb + h;
    for (int t = 0; t < 22; ++t) {
        const int i = t * 16 + wid * 4 + grp;
        const int ig = min(i, N_TOK - 1);
        const float4 q1 = *(const float4*)&q1s[ig * 4];
        const float4 q2 = *(const float4*)&q2s[ig * 4];
        const int* relRow = rel + (size_t)ig * N_TOK;
        float sum = 0.f, a0 = 0.f, a1 = 0.f, a2 = 0.f, a3 = 0.f;
        #pragma unroll 4
        for (int it = 0; it < 22; ++it) {
            const int jj = it * 16 + l16;
            float s = (jj < N_TOK) ? rpbh[relRow[jj] * H_HEADS] * LOG2E : -16384.f;
            const float4 k1 = *(const float4*)&k1s[jj * 4];
            const float4 k2 = *(const float4*)&k2s[jj * 4];
            s = fmaf(q1.x, k1.x, s); s = fmaf(q1.y, k1.y, s);
            s = fmaf(q1.z, k1.z, s); s = fmaf(q1.w, k1.w, s);
            s = fmaf(q2.x, k2.x, s); s = fmaf(q2.y, k2.y, s);
            s = fmaf(q2.z, k2.z, s); s = fmaf(q2.w, k2.w, s);
            const float p = exp2f(s);
            const float4 v = *(const float4*)&vs[jj * 4];
            sum += p;
            a0 = fmaf(p, v.x, a0); a1 = fmaf(p, v.y, a1);
            a2 = fmaf(p, v.z, a2); a3 = fmaf(p, v.w, a3);
        }
        #pragma unroll
        for (int o = 8; o; o >>= 1) {
            sum += __shfl_xor(sum, o, 16);
            a0 += __shfl_xor(a0, o, 16); a1 += __shfl_xor(a1, o, 16);
            a2 += __shfl_xor(a2, o, 16); a3 += __shfl_xor(a3, o, 16);
        }
        if (l16 == 0 && i < N_TOK) {
            const float inv = 1.f / sum;
            float* op = ao + ((size_t)b * N_TOK + i) * C_DIM + h * HD;
            *(float4*)op = make_float4(a0 * inv, a1 * inv, a2 * inv, a3 * inv);
        }
    }
}

// ---------------- kernel 4: output projection (merges attn partials) -> float32 ----------------
__global__ __launch_bounds__(256) void proj_kernel(const float* __restrict__ ao,
                                                   const float* __restrict__ Pa,
                                                   const float* __restrict__ Ps,
                                                   const float* __restrict__ pw,
                                                   const float* __restrict__ pb,
                                                   float* __restrict__ out,
                                                   int split) {
    __shared__ float xs[32 * C_DIM];
    __shared__ float pwl[C_DIM * 97];
    const int b = blockIdx.y, row0 = blockIdx.x * 32;
    const int rows = min(32, N_TOK - row0);
    if (split) {
        const float* Pa1 = Pa + AP;
        const float* Ps1 = Ps + PS_HALF;
        for (int e = threadIdx.x; e < rows * C_DIM; e += blockDim.x) {
            int r = e / C_DIM, c = e - r * C_DIM;
            int h = c >> 2, d = c & 3;
            size_t pi = ((size_t)b * H_HEADS + h) * N_PAD + row0 + r;
            float s = Ps[pi] + Ps1[pi];
            float num = Pa[pi * 4 + d] + Pa1[pi * 4 + d];
            xs[e] = num / s;
        }
    } else {
        for (int e = threadIdx.x; e < rows * C_DIM; e += blockDim.x)
            xs[e] = ao[((size_t)b * N_TOK + row0) * C_DIM + e];
    }
    for (int e = threadIdx.x; e < C_DIM * C_DIM; e += blockDim.x) {
        int c = e / C_DIM, k = e - c * C_DIM;
        pwl[c * 97 + k] = pw[e];
    }
    __syncthreads();
    for (int e = threadIdx.x; e < rows * C_DIM; e += blockDim.x) {
        int r = e / C_DIM, c = e - r * C_DIM;
        float acc = pb[c];
        const float* xr = xs + r * C_DIM;
        const float* wr = pwl + c * 97;
        #pragma unroll 8
        for (int k = 0; k < C_DIM; ++k) acc += xr[k] * wr[k];
        out[((size_t)b * N_TOK + row0) * C_DIM + e] = acc;
    }
}

static const void* find_by_size(void* const* d_in, const int* in_sizes, int n_in,
                                int want, int occurrence) {
    int seen = 0;
    for (int i = 0; i < n_in; ++i) {
        if (in_sizes[i] == want) {
            if (seen == occurrence) return d_in[i];
            ++seen;
        }
    }
    return nullptr;
}

extern "C" void kernel_launch(void* const* d_in, const int* in_sizes, int n_in,
                              void* d_out, int out_size, void* d_ws, size_t ws_size,
                              hipStream_t stream) {
    const float* x1     = (const float*)find_by_size(d_in, in_sizes, n_in, 1053696, 0);
    const float* x2     = (const float*)find_by_size(d_in, in_sizes, n_in, 1053696, 1);
    const float* qkv_w  = (const float*)find_by_size(d_in, in_sizes, n_in, 27648, 0);
    const float* qkv_b  = (const float*)find_by_size(d_in, in_sizes, n_in, 288, 0);
    const float* proj_w = (const float*)find_by_size(d_in, in_sizes, n_in, 9216, 0);
    const float* proj_b = (const float*)find_by_size(d_in, in_sizes, n_in, 96, 0);
    const float* rpb    = (const float*)find_by_size(d_in, in_sizes, n_in, 52728, 0);
    const float* fuse_w = (const float*)find_by_size(d_in, in_sizes, n_in, 1152, 0);
    const float* fuse_b = (const float*)find_by_size(d_in, in_sizes, n_in, 24, 0);
    const int*   rel    = (const int*)  find_by_size(d_in, in_sizes, n_in, 117649, 0);

    if (!x1 || !x2 || !qkv_w || !qkv_b || !proj_w || !proj_b || !rpb || !fuse_w ||
        !fuse_b || !rel) {
        x1     = (const float*)d_in[0];
        x2     = (const float*)d_in[1];
        qkv_w  = (const float*)d_in[2];
        qkv_b  = (const float*)d_in[3];
        proj_w = (const float*)d_in[4];
        proj_b = (const float*)d_in[5];
        rpb    = (const float*)d_in[6];
        fuse_w = (const float*)d_in[7];
        fuse_b = (const float*)d_in[8];
        rel    = (const int*)d_in[9];
    }

    float* ws = (float*)d_ws;
    float* V1 = ws + 4 * AP;
    float* V2 = ws + 5 * AP;
    float* VF = ws + 6 * AP;
    float* AO = V1;            // alias: v1 dead after fuse (fallback paths only)
    float* BT = ws + 7 * AP;
    float* PA = BT + BT_ELEMS;             // 2 halves x AP
    float* PS = PA + 2 * AP;               // 2 halves x PS_HALF
    float* out = (float*)d_out;

    const bool use_bias  = ws_size >= (7 * AP + BT_ELEMS) * sizeof(float);
    const bool use_split = ws_size >= (7 * AP + BT_ELEMS + 2 * AP + 2 * PS_HALF) * sizeof(float);

    const int prep_blocks = use_bias ? 5016 : 2112;
    prep_kernel<<<prep_blocks, 192, 0, stream>>>(x1, x2, qkv_w, qkv_b, rpb, rel, ws, BT);
    fuse_kernel<<<dim3(H_HEADS, B_WIN), 256, 0, stream>>>(V1, V2, fuse_w, fuse_b, VF);
    if (use_bias && use_split) {
        attn_part<<<dim3(H_HEADS, B_WIN, 2), 192, 0, stream>>>(ws, BT, VF, PA, PS);
        proj_kernel<<<dim3(11, B_WIN), 256, 0, stream>>>(nullptr, PA, PS, proj_w, proj_b, out, 1);
    } else {
        if (use_bias)
            attn_full<<<dim3(H_HEADS, B_WIN), 192, 0, stream>>>(ws, BT, VF, AO);
        else
            attn_kernel_g<<<dim3(H_HEADS, B_WIN), 256, 0, stream>>>(ws, rpb, rel, VF, AO);
        proj_kernel<<<dim3(11, B_WIN), 256, 0, stream>>>(AO, nullptr, nullptr, proj_w, proj_b, out, 0);
    }
}

// Round 14
// 203.343 us; speedup vs baseline: 1.1668x; 1.0086x over previous
//
#include <hip/hip_runtime.h>
#include <hip/hip_bf16.h>

#define N_TOK 343
#define N_PAD 344
#define BT_J 352                  // bias j-extent (padded: 44 batches of 8)
#define C_DIM 96
#define H_HEADS 24
#define HD 4
#define B_WIN 32
#define LOG2E 1.4426950408889634f
#define SCALE_Q (0.5f * LOG2E)
#define EPS_IN 1e-5f
#define CH_STR (HD * N_PAD)                    // 1376 floats per (b,h)
#define F4_STR (N_PAD)                         // 344 float4 per (b,h)
#define AP ((size_t)B_WIN * H_HEADS * CH_STR)  // 1,056,768 floats per slot
#define BT_ELEMS ((size_t)H_HEADS * BT_J * N_PAD)
#define PS_HALF ((size_t)B_WIN * H_HEADS * N_PAD)
// q/k/v/vf slots: [b][h][n][d] (float4 per token), token row 343 = zero pad
// ws: [0..7AP) q1,k1,q2,k2,v1(->AO),v2,vf | [7AP..) bT | Pa parts | Ps parts

typedef float v2f __attribute__((ext_vector_type(2)));
#define FMA2(a, b, c) __builtin_elementwise_fma(a, b, c)

// ---------------- kernel 1: prep = {QKV GEMM (src-split) | biasT gather} ----------------
__global__ __launch_bounds__(192) void prep_kernel(const float* __restrict__ x1,
                                                   const float* __restrict__ x2,
                                                   const float* __restrict__ w,
                                                   const float* __restrict__ bqkv,
                                                   const float* __restrict__ rpb,
                                                   const int* __restrict__ rel,
                                                   float* __restrict__ ws,
                                                   float* __restrict__ bT) {
    __shared__ float smem[12704];
    const int bid = blockIdx.x, tid = threadIdx.x;
    if (bid < 2112) {
        const int r0t = bid % 11;
        const int rest = bid / 11;
        const int sy = rest % 6, b = rest / 6;
        const int s = sy >> 1, src = sy & 1;
        const int r0 = r0t * 32;
        const int rows = min(32, N_TOK - r0);
        float* xs = smem;                      // [32][97]
        float* wt = smem + 3104;               // [96][100]
        for (int e = tid; e < 96 * 96; e += 192) {
            int j = e / 96, k = e - j * 96;
            wt[k * 100 + j] = w[s * 96 * 96 + e];
        }
        const float* xp = (src == 0 ? x1 : x2) + ((size_t)b * N_TOK + r0) * C_DIM;
        for (int e = tid; e < rows * 96; e += 192) {
            int r = e / 96, k = e - r * 96;
            xs[r * 97 + k] = xp[e];
        }
        __syncthreads();
        const int rg = tid & 7, og = tid >> 3;
        const int oc0 = og * 4, rr = rg * 4;
        float acc[4][4];
        #pragma unroll
        for (int i = 0; i < 4; ++i) {
            float bv = bqkv[s * 96 + oc0 + i];
            #pragma unroll
            for (int j = 0; j < 4; ++j) acc[i][j] = bv;
        }
        for (int k = 0; k < 96; ++k) {
            float4 w4 = *(const float4*)&wt[k * 100 + oc0];
            float wv[4] = {w4.x, w4.y, w4.z, w4.w};
            float xv[4];
            #pragma unroll
            for (int j = 0; j < 4; ++j) xv[j] = xs[(rr + j) * 97 + k];
            #pragma unroll
            for (int i = 0; i < 4; ++i)
                #pragma unroll
                for (int j = 0; j < 4; ++j) acc[i][j] += xv[j] * wv[i];
        }
        const float scl = (s == 0) ? SCALE_Q : 1.0f;
        const int slot = (s == 0) ? (src ? 2 : 0) : (s == 1) ? (src ? 3 : 1) : (src ? 5 : 4);
        #pragma unroll
        for (int j = 0; j < 4; ++j) {
            int row = r0 + rr + j;
            if (row > N_TOK) continue;
            size_t base = (((size_t)b * H_HEADS + og) * N_PAD + row) * 4;
            float4 val = (row == N_TOK)
                ? make_float4(0.f, 0.f, 0.f, 0.f)
                : make_float4(acc[0][j] * scl, acc[1][j] * scl,
                              acc[2][j] * scl, acc[3][j] * scl);
            *(float4*)(ws + (size_t)slot * AP + base) = val;
        }
    } else {
        const int bid2 = bid - 2112;
        const int h = bid2 / 121;
        const int t = bid2 - h * 121;
        const int ti = t / 11, tj = t - ti * 11;
        const int i0 = ti * 32, j0 = tj * 32;
        float* tile = smem;                    // [32][33]
        for (int e = tid; e < 1024; e += 192) {
            int r = e >> 5, c = e & 31;
            int i = i0 + r, j = j0 + c;
            float v = -16384.f;
            if (i < N_TOK && j < N_TOK) v = rpb[rel[i * N_TOK + j] * H_HEADS + h] * LOG2E;
            tile[r * 33 + c] = v;
        }
        __syncthreads();
        for (int e = tid; e < 1024; e += 192) {
            int c = e >> 5, r = e & 31;
            int i = i0 + r, j = j0 + c;
            if (i < N_PAD)
                bT[((size_t)h * BT_J + j) * N_PAD + i] = tile[r * 33 + c];
        }
    }
}

// ---------------- kernel 2: fuse, float4 ----------------
__global__ __launch_bounds__(256) void fuse_kernel(const float* __restrict__ v1,
                                                   const float* __restrict__ v2,
                                                   const float* __restrict__ fw,
                                                   const float* __restrict__ fb,
                                                   float* __restrict__ vf) {
    const int o = blockIdx.x, b = blockIdx.y;
    __shared__ float4 ts4[343];
    __shared__ float red[32];
    __shared__ float fwl[48];
    if (threadIdx.x < 48) fwl[threadIdx.x] = fw[o * 48 + threadIdx.x];
    __syncthreads();
    const float bo = fb[o];
    const float4* p1 = (const float4*)(v1 + (size_t)b * H_HEADS * CH_STR);
    const float4* p2 = (const float4*)(v2 + (size_t)b * H_HEADS * CH_STR);
    float lsum = 0.f, lsq = 0.f;
    for (int e = threadIdx.x; e < 343; e += blockDim.x) {
        float4 acc = make_float4(bo, bo, bo, bo);
        #pragma unroll
        for (int c = 0; c < H_HEADS; ++c) {
            float4 u1 = p1[(size_t)c * F4_STR + e];
            float4 u2 = p2[(size_t)c * F4_STR + e];
            float w1 = fwl[c], w2 = fwl[24 + c];
            acc.x += w1 * u1.x + w2 * u2.x;
            acc.y += w1 * u1.y + w2 * u2.y;
            acc.z += w1 * u1.z + w2 * u2.z;
            acc.w += w1 * u1.w + w2 * u2.w;
        }
        ts4[e] = acc;
        lsum += acc.x + acc.y + acc.z + acc.w;
        lsq += acc.x * acc.x + acc.y * acc.y + acc.z * acc.z + acc.w * acc.w;
    }
    for (int off = 32; off; off >>= 1) {
        lsum += __shfl_xor(lsum, off);
        lsq  += __shfl_xor(lsq, off);
    }
    int wid = threadIdx.x >> 6, lane = threadIdx.x & 63;
    if (lane == 0) { red[wid] = lsum; red[8 + wid] = lsq; }
    __syncthreads();
    if (threadIdx.x == 0) {
        float su = red[0] + red[1] + red[2] + red[3];
        float q  = red[8] + red[9] + red[10] + red[11];
        float mean = su / (float)(N_TOK * HD);
        float var  = q / (float)(N_TOK * HD) - mean * mean;
        red[16] = mean;
        red[17] = rsqrtf(var + EPS_IN);
    }
    __syncthreads();
    const float mean = red[16], inv = red[17];
    float4* outp = (float4*)(vf + ((size_t)b * H_HEADS + o) * CH_STR);
    for (int e = threadIdx.x; e < 343; e += blockDim.x) {
        float4 x = ts4[e];
        float4 r;
        r.x = 1.f / (1.f + __expf(-fmaxf((x.x - mean) * inv, 0.f)));
        r.y = 1.f / (1.f + __expf(-fmaxf((x.y - mean) * inv, 0.f)));
        r.z = 1.f / (1.f + __expf(-fmaxf((x.z - mean) * inv, 0.f)));
        r.w = 1.f / (1.f + __expf(-fmaxf((x.w - mean) * inv, 0.f)));
        outp[e] = r;
    }
}

// ---------------- kernel 3a: attention v7 — 4 rows/lane, 2 heads/block, partials ----------------
struct JB4 { float4 bv[4], k1[4], k2[4], vv[4]; };

#define LOAD4(B_, j0_)                                  \
    _Pragma("unroll")                                   \
    for (int u = 0; u < 4; ++u) {                       \
        B_.bv[u] = bPf[((j0_) + u) * 86];               \
        B_.k1[u] = K1[(j0_) + u];                       \
        B_.k2[u] = K2[(j0_) + u];                       \
        B_.vv[u] = Vv[(j0_) + u];                       \
    }

#define COMP4(B_)                                                           \
    _Pragma("unroll")                                                       \
    for (int u = 0; u < 4; ++u) {                                           \
        const float4 bb = B_.bv[u];                                         \
        const float4 k1 = B_.k1[u], k2 = B_.k2[u], v = B_.vv[u];            \
        v2f sP = {bb.x, bb.y}, sQ = {bb.z, bb.w};                           \
        sP = FMA2((v2f)(k1.x), q1P0, sP); sP = FMA2((v2f)(k1.y), q1P1, sP); \
        sP = FMA2((v2f)(k1.z), q1P2, sP); sP = FMA2((v2f)(k1.w), q1P3, sP); \
        sP = FMA2((v2f)(k2.x), q2P0, sP); sP = FMA2((v2f)(k2.y), q2P1, sP); \
        sP = FMA2((v2f)(k2.z), q2P2, sP); sP = FMA2((v2f)(k2.w), q2P3, sP); \
        sQ = FMA2((v2f)(k1.x), q1Q0, sQ); sQ = FMA2((v2f)(k1.y), q1Q1, sQ); \
        sQ = FMA2((v2f)(k1.z), q1Q2, sQ); sQ = FMA2((v2f)(k1.w), q1Q3, sQ); \
        sQ = FMA2((v2f)(k2.x), q2Q0, sQ); sQ = FMA2((v2f)(k2.y), q2Q1, sQ); \
        sQ = FMA2((v2f)(k2.z), q2Q2, sQ); sQ = FMA2((v2f)(k2.w), q2Q3, sQ); \
        const v2f pP = {exp2f(sP.x), exp2f(sP.y)};                          \
        const v2f pQ = {exp2f(sQ.x), exp2f(sQ.y)};                          \
        sumP += pP; sumQ += pQ;                                             \
        aP0 = FMA2(pP, (v2f)(v.x), aP0); aP1 = FMA2(pP, (v2f)(v.y), aP1);   \
        aP2 = FMA2(pP, (v2f)(v.z), aP2); aP3 = FMA2(pP, (v2f)(v.w), aP3);   \
        aQ0 = FMA2(pQ, (v2f)(v.x), aQ0); aQ1 = FMA2(pQ, (v2f)(v.y), aQ1);   \
        aQ2 = FMA2(pQ, (v2f)(v.z), aQ2); aQ3 = FMA2(pQ, (v2f)(v.w), aQ3);   \
    }

__global__ __launch_bounds__(192) void attn_part4(const float* __restrict__ ws,
                                                  const float* __restrict__ bT,
                                                  const float* __restrict__ vf,
                                                  float* __restrict__ Pa,
                                                  float* __restrict__ Ps,
                                                  int jspan, int nbatch) {
    const int hp = blockIdx.x, b = blockIdx.y, part = blockIdx.z;
    const int l = threadIdx.x;
    if (l >= 172) return;
    const int hs = (l >= 86);
    const int h = hp * 2 + hs;
    const int r0 = (hs ? l - 86 : l) * 4;      // rows r0..r0+3 (r0+3==343 pad at last lane)
    const int j0 = part * jspan;
    const size_t bh = (size_t)b * H_HEADS + h;
    const float4* __restrict__ K1 = (const float4*)(ws + 1 * AP) + bh * F4_STR + j0;
    const float4* __restrict__ K2 = (const float4*)(ws + 3 * AP) + bh * F4_STR + j0;
    const float4* __restrict__ Vv = (const float4*)vf + bh * F4_STR + j0;
    const float4* __restrict__ Q1 = (const float4*)ws + bh * F4_STR;
    const float4* __restrict__ Q2 = (const float4*)(ws + 2 * AP) + bh * F4_STR;
    const float4* __restrict__ bPf = (const float4*)bT + ((size_t)h * BT_J + j0) * 86 + (r0 >> 2);
    float4 q1r[4], q2r[4];
    #pragma unroll
    for (int t = 0; t < 4; ++t) { q1r[t] = Q1[r0 + t]; q2r[t] = Q2[r0 + t]; }
    const v2f q1P0 = {q1r[0].x, q1r[1].x}, q1P1 = {q1r[0].y, q1r[1].y},
              q1P2 = {q1r[0].z, q1r[1].z}, q1P3 = {q1r[0].w, q1r[1].w};
    const v2f q1Q0 = {q1r[2].x, q1r[3].x}, q1Q1 = {q1r[2].y, q1r[3].y},
              q1Q2 = {q1r[2].z, q1r[3].z}, q1Q3 = {q1r[2].w, q1r[3].w};
    const v2f q2P0 = {q2r[0].x, q2r[1].x}, q2P1 = {q2r[0].y, q2r[1].y},
              q2P2 = {q2r[0].z, q2r[1].z}, q2P3 = {q2r[0].w, q2r[1].w};
    const v2f q2Q0 = {q2r[2].x, q2r[3].x}, q2Q1 = {q2r[2].y, q2r[3].y},
              q2Q2 = {q2r[2].z, q2r[3].z}, q2Q3 = {q2r[2].w, q2r[3].w};
    v2f sumP = {0.f, 0.f}, sumQ = {0.f, 0.f};
    v2f aP0 = {0.f,0.f}, aP1 = {0.f,0.f}, aP2 = {0.f,0.f}, aP3 = {0.f,0.f};
    v2f aQ0 = {0.f,0.f}, aQ1 = {0.f,0.f}, aQ2 = {0.f,0.f}, aQ3 = {0.f,0.f};
    JB4 A, B;
    LOAD4(A, 0)
    LOAD4(B, 4)
    for (int t = 0; t < nbatch; ++t) {
        const int jb = t * 8;
        COMP4(A)
        if (t < nbatch - 1) { LOAD4(A, jb + 8) }
        COMP4(B)
        if (t < nbatch - 1) { LOAD4(B, jb + 12) }
    }
    float* PaH = Pa + (size_t)part * AP;
    float* PsH = Ps + (size_t)part * PS_HALF;
    const size_t pi = bh * N_PAD + r0;
    *(float4*)(PaH + (pi + 0) * 4) = make_float4(aP0.x, aP1.x, aP2.x, aP3.x);
    *(float4*)(PaH + (pi + 1) * 4) = make_float4(aP0.y, aP1.y, aP2.y, aP3.y);
    *(float4*)(PaH + (pi + 2) * 4) = make_float4(aQ0.x, aQ1.x, aQ2.x, aQ3.x);
    *(float4*)(PaH + (pi + 3) * 4) = make_float4(aQ0.y, aQ1.y, aQ2.y, aQ3.y);
    *(float4*)(PsH + pi) = make_float4(sumP.x, sumP.y, sumQ.x, sumQ.y);
}

// ---------------- kernel 3b: r13 2-row attn partials (2-way tier) ----------------
struct JBatch { v2f bv[4]; float4 k1[4], k2[4], vv[4]; };

#define LOAD_BATCH(B_, j0_)                                            \
    _Pragma("unroll")                                                  \
    for (int u = 0; u < 4; ++u) {                                      \
        B_.bv[u] = *(const v2f*)(bP + (size_t)((j0_) + u) * N_PAD);    \
        B_.k1[u] = K1[(j0_) + u];                                      \
        B_.k2[u] = K2[(j0_) + u];                                      \
        B_.vv[u] = Vv[(j0_) + u];                                      \
    }

#define COMP_BATCH(B_)                                                 \
    _Pragma("unroll")                                                  \
    for (int u = 0; u < 4; ++u) {                                      \
        const float4 k1 = B_.k1[u], k2 = B_.k2[u], v = B_.vv[u];       \
        v2f s2 = B_.bv[u];                                             \
        s2 = FMA2((v2f)(k1.x), q1p0, s2); s2 = FMA2((v2f)(k1.y), q1p1, s2); \
        s2 = FMA2((v2f)(k1.z), q1p2, s2); s2 = FMA2((v2f)(k1.w), q1p3, s2); \
        s2 = FMA2((v2f)(k2.x), q2p0, s2); s2 = FMA2((v2f)(k2.y), q2p1, s2); \
        s2 = FMA2((v2f)(k2.z), q2p2, s2); s2 = FMA2((v2f)(k2.w), q2p3, s2); \
        const v2f p2 = {exp2f(s2.x), exp2f(s2.y)};                     \
        sum2 += p2;                                                    \
        a0 = FMA2(p2, (v2f)(v.x), a0); a1 = FMA2(p2, (v2f)(v.y), a1);  \
        a2 = FMA2(p2, (v2f)(v.z), a2); a3 = FMA2(p2, (v2f)(v.w), a3);  \
    }

#define ATTN_SETUP                                                                 \
    const size_t off = ((size_t)b * H_HEADS + h) * CH_STR;                         \
    const float4* __restrict__ K1 = (const float4*)(ws + 1 * AP + off);            \
    const float4* __restrict__ K2 = (const float4*)(ws + 3 * AP + off);            \
    const float4* __restrict__ Vv = (const float4*)(vf + off);                     \
    const float*  __restrict__ Q1 = ws + 0 * AP + off;                             \
    const float*  __restrict__ Q2 = ws + 2 * AP + off;                             \
    const int rA = l * 2, rB = rA + 1;                                             \
    const float4 q1a = *(const float4*)&Q1[rA * 4];                                \
    const float4 q1b = *(const float4*)&Q1[rB * 4];                                \
    const float4 q2a = *(const float4*)&Q2[rA * 4];                                \
    const float4 q2b = *(const float4*)&Q2[rB * 4];                                \
    const v2f q1p0 = {q1a.x, q1b.x}, q1p1 = {q1a.y, q1b.y},                        \
              q1p2 = {q1a.z, q1b.z}, q1p3 = {q1a.w, q1b.w};                        \
    const v2f q2p0 = {q2a.x, q2b.x}, q2p1 = {q2a.y, q2b.y},                        \
              q2p2 = {q2a.z, q2b.z}, q2p3 = {q2a.w, q2b.w};                        \
    v2f sum2 = {0.f, 0.f};                                                         \
    v2f a0 = {0.f, 0.f}, a1 = {0.f, 0.f}, a2 = {0.f, 0.f}, a3 = {0.f, 0.f};

__global__ __launch_bounds__(192) void attn_part2(const float* __restrict__ ws,
                                                  const float* __restrict__ bT,
                                                  const float* __restrict__ vf,
                                                  float* __restrict__ Pa,
                                                  float* __restrict__ Ps) {
    const int h = blockIdx.x, b = blockIdx.y, half = blockIdx.z;
    const int l = threadIdx.x;
    if (l >= 172) return;
    ATTN_SETUP
    const int j0h = half * 176;
    const float* bP = bT + ((size_t)h * BT_J + j0h) * N_PAD + rA;
    K1 += j0h; K2 += j0h; Vv += j0h;
    JBatch A, B;
    LOAD_BATCH(A, 0)
    LOAD_BATCH(B, 4)
    for (int t = 0; t < 22; ++t) {
        const int jb = t * 8;
        COMP_BATCH(A)
        if (t < 21) { LOAD_BATCH(A, jb + 8) }
        COMP_BATCH(B)
        if (t < 21) { LOAD_BATCH(B, jb + 12) }
    }
    float* PaH = Pa + (size_t)half * AP;
    float* PsH = Ps + (size_t)half * PS_HALF;
    const size_t pi = ((size_t)b * H_HEADS + h) * N_PAD;
    *(float4*)(PaH + (pi + rA) * 4) = make_float4(a0.x, a1.x, a2.x, a3.x);
    *(float4*)(PaH + (pi + rB) * 4) = make_float4(a0.y, a1.y, a2.y, a3.y);
    PsH[pi + rA] = sum2.x;
    PsH[pi + rB] = sum2.y;
}

// ---------------- kernel 3c: full-j attention (no-partial fallback) ----------------
__global__ __launch_bounds__(192) void attn_full(const float* __restrict__ ws,
                                                 const float* __restrict__ bT,
                                                 const float* __restrict__ vf,
                                                 float* __restrict__ ao) {
    const int h = blockIdx.x, b = blockIdx.y;
    const int l = threadIdx.x;
    if (l >= 172) return;
    ATTN_SETUP
    const float* bP = bT + (size_t)h * BT_J * N_PAD + rA;
    JBatch A, B;
    LOAD_BATCH(A, 0)
    LOAD_BATCH(B, 4)
    for (int t = 0; t < 43; ++t) {
        const int jb = t * 8;
        COMP_BATCH(A)
        if (t < 42) { LOAD_BATCH(A, jb + 8) }
        COMP_BATCH(B)
        if (t < 42) { LOAD_BATCH(B, jb + 12) }
    }
    {
        const float inv = 1.f / sum2.x;
        float* op = ao + ((size_t)b * N_TOK + rA) * C_DIM + h * HD;
        *(float4*)op = make_float4(a0.x * inv, a1.x * inv, a2.x * inv, a3.x * inv);
    }
    if (rB < N_TOK) {
        const float inv = 1.f / sum2.y;
        float* op = ao + ((size_t)b * N_TOK + rB) * C_DIM + h * HD;
        *(float4*)op = make_float4(a0.y * inv, a1.y * inv, a2.y * inv, a3.y * inv);
    }
}

// ---------------- kernel 3d: gather fallback ----------------
__global__ __launch_bounds__(256) void attn_kernel_g(const float* __restrict__ ws,
                                                     const float* __restrict__ rpb,
                                                     const int* __restrict__ rel,
                                                     const float* __restrict__ vf,
                                                     float* __restrict__ ao) {
    const int h = blockIdx.x, b = blockIdx.y;
    __shared__ float k1s[BT_J * 4], k2s[BT_J * 4], vs[BT_J * 4];
    __shared__ float q1s[N_PAD * 4], q2s[N_PAD * 4];
    const size_t off = ((size_t)b * H_HEADS + h) * CH_STR;
    const float* Q1 = ws + 0 * AP + off;
    const float* K1 = ws + 1 * AP + off;
    const float* Q2 = ws + 2 * AP + off;
    const float* K2 = ws + 3 * AP + off;
    const float* V  = vf + off;
    const int tid = threadIdx.x;
    for (int e = tid; e < N_PAD * 4; e += 256) {
        k1s[e] = K1[e]; k2s[e] = K2[e]; vs[e] = V[e];
        q1s[e] = Q1[e]; q2s[e] = Q2[e];
    }
    for (int e = N_PAD * 4 + tid; e < BT_J * 4; e += 256) {
        k1s[e] = 0.f; k2s[e] = 0.f; vs[e] = 0.f;
    }
    __syncthreads();
    const int wid = tid >> 6, lane = tid & 63;
    const int grp = lane >> 4, l16 = lane & 15;
    const float* rpbh = rpb + h;
    for (int t = 0; t < 22; ++t) {
        const int i = t * 16 + wid * 4 + grp;
        const int ig = min(i, N_TOK - 1);
        const float4 q1 = *(const float4*)&q1s[ig * 4];
        const float4 q2 = *(const float4*)&q2s[ig * 4];
        const int* relRow = rel + (size_t)ig * N_TOK;
        float sum = 0.f, a0 = 0.f, a1 = 0.f, a2 = 0.f, a3 = 0.f;
        #pragma unroll 4
        for (int it = 0; it < 22; ++it) {
            const int jj = it * 16 + l16;
            float s = (jj < N_TOK) ? rpbh[relRow[jj] * H_HEADS] * LOG2E : -16384.f;
            const float4 k1 = *(const float4*)&k1s[jj * 4];
            const float4 k2 = *(const float4*)&k2s[jj * 4];
            s = fmaf(q1.x, k1.x, s); s = fmaf(q1.y, k1.y, s);
            s = fmaf(q1.z, k1.z, s); s = fmaf(q1.w, k1.w, s);
            s = fmaf(q2.x, k2.x, s); s = fmaf(q2.y, k2.y, s);
            s = fmaf(q2.z, k2.z, s); s = fmaf(q2.w, k2.w, s);
            const float p = exp2f(s);
            const float4 v = *(const float4*)&vs[jj * 4];
            sum += p;
            a0 = fmaf(p, v.x, a0); a1 = fmaf(p, v.y, a1);
            a2 = fmaf(p, v.z, a2); a3 = fmaf(p, v.w, a3);
        }
        #pragma unroll
        for (int o = 8; o; o >>= 1) {
            sum += __shfl_xor(sum, o, 16);
            a0 += __shfl_xor(a0, o, 16); a1 += __shfl_xor(a1, o, 16);
            a2 += __shfl_xor(a2, o, 16); a3 += __shfl_xor(a3, o, 16);
        }
        if (l16 == 0 && i < N_TOK) {
            const float inv = 1.f / sum;
            float* op = ao + ((size_t)b * N_TOK + i) * C_DIM + h * HD;
            *(float4*)op = make_float4(a0 * inv, a1 * inv, a2 * inv, a3 * inv);
        }
    }
}

// ---------------- kernel 4: output projection — register-blocked GEMM + partial merge ----------------
__global__ __launch_bounds__(192) void proj_kernel(const float* __restrict__ ao,
                                                   const float* __restrict__ Pa,
                                                   const float* __restrict__ Ps,
                                                   const float* __restrict__ pw,
                                                   const float* __restrict__ pb,
                                                   float* __restrict__ out,
                                                   int split) {
    __shared__ float xs[32 * 97];
    __shared__ float wt[96 * 100];
    __shared__ float sinv[32 * 24];
    const int b = blockIdx.y, row0 = blockIdx.x * 32;
    const int rows = min(32, N_TOK - row0);
    const int tid = threadIdx.x;
    for (int e = tid; e < 96 * 96; e += 192) {
        int c = e / 96, k = e - c * 96;
        wt[k * 100 + c] = pw[e];
    }
    if (split) {
        for (int e = tid; e < rows * 24; e += 192) {
            int r = e / 24, h = e - r * 24;
            size_t pi = ((size_t)b * H_HEADS + h) * N_PAD + row0 + r;
            float s = 0.f;
            for (int p = 0; p < split; ++p) s += Ps[(size_t)p * PS_HALF + pi];
            sinv[r * 24 + h] = 1.f / s;
        }
        __syncthreads();
        for (int e = tid; e < rows * 96; e += 192) {
            int r = e / 96, c = e - r * 96;
            int h = c >> 2, d = c & 3;
            size_t pi = ((size_t)b * H_HEADS + h) * N_PAD + row0 + r;
            float num = 0.f;
            for (int p = 0; p < split; ++p) num += Pa[(size_t)p * AP + pi * 4 + d];
            xs[r * 97 + c] = num * sinv[r * 24 + h];
        }
    } else {
        for (int e = tid; e < rows * 96; e += 192) {
            int r = e / 96, c = e - r * 96;
            xs[r * 97 + c] = ao[((size_t)b * N_TOK + row0) * C_DIM + e];
        }
    }
    __syncthreads();
    const int rg = tid & 7, og = tid >> 3;
    const int oc0 = og * 4, rr = rg * 4;
    float acc[4][4];
    #pragma unroll
    for (int i = 0; i < 4; ++i) {
        float bv = pb[oc0 + i];
        #pragma unroll
        for (int j = 0; j < 4; ++j) acc[i][j] = bv;
    }
    for (int k = 0; k < 96; ++k) {
        float4 w4 = *(const float4*)&wt[k * 100 + oc0];
        float wv[4] = {w4.x, w4.y, w4.z, w4.w};
        float xv[4];
        #pragma unroll
        for (int j = 0; j < 4; ++j) xv[j] = xs[(rr + j) * 97 + k];
        #pragma unroll
        for (int i = 0; i < 4; ++i)
            #pragma unroll
            for (int j = 0; j < 4; ++j) acc[i][j] += xv[j] * wv[i];
    }
    #pragma unroll
    for (int j = 0; j < 4; ++j) {
        int row = row0 + rr + j;
        if (row >= N_TOK) continue;
        *(float4*)(out + ((size_t)b * N_TOK + row) * C_DIM + oc0) =
            make_float4(acc[0][j], acc[1][j], acc[2][j], acc[3][j]);
    }
}

static const void* find_by_size(void* const* d_in, const int* in_sizes, int n_in,
                                int want, int occurrence) {
    int seen = 0;
    for (int i = 0; i < n_in; ++i) {
        if (in_sizes[i] == want) {
            if (seen == occurrence) return d_in[i];
            ++seen;
        }
    }
    return nullptr;
}

extern "C" void kernel_launch(void* const* d_in, const int* in_sizes, int n_in,
                              void* d_out, int out_size, void* d_ws, size_t ws_size,
                              hipStream_t stream) {
    const float* x1     = (const float*)find_by_size(d_in, in_sizes, n_in, 1053696, 0);
    const float* x2     = (const float*)find_by_size(d_in, in_sizes, n_in, 1053696, 1);
    const float* qkv_w  = (const float*)find_by_size(d_in, in_sizes, n_in, 27648, 0);
    const float* qkv_b  = (const float*)find_by_size(d_in, in_sizes, n_in, 288, 0);
    const float* proj_w = (const float*)find_by_size(d_in, in_sizes, n_in, 9216, 0);
    const float* proj_b = (const float*)find_by_size(d_in, in_sizes, n_in, 96, 0);
    const float* rpb    = (const float*)find_by_size(d_in, in_sizes, n_in, 52728, 0);
    const float* fuse_w = (const float*)find_by_size(d_in, in_sizes, n_in, 1152, 0);
    const float* fuse_b = (const float*)find_by_size(d_in, in_sizes, n_in, 24, 0);
    const int*   rel    = (const int*)  find_by_size(d_in, in_sizes, n_in, 117649, 0);

    if (!x1 || !x2 || !qkv_w || !qkv_b || !proj_w || !proj_b || !rpb || !fuse_w ||
        !fuse_b || !rel) {
        x1     = (const float*)d_in[0];
        x2     = (const float*)d_in[1];
        qkv_w  = (const float*)d_in[2];
        qkv_b  = (const float*)d_in[3];
        proj_w = (const float*)d_in[4];
        proj_b = (const float*)d_in[5];
        rpb    = (const float*)d_in[6];
        fuse_w = (const float*)d_in[7];
        fuse_b = (const float*)d_in[8];
        rel    = (const int*)d_in[9];
    }

    float* ws = (float*)d_ws;
    float* V1 = ws + 4 * AP;
    float* V2 = ws + 5 * AP;
    float* VF = ws + 6 * AP;
    float* AO = V1;
    float* BT = ws + 7 * AP;
    float* PA = BT + BT_ELEMS;
    float* PS4 = PA + 4 * AP;
    float* PS2 = PA + 2 * AP;
    float* out = (float*)d_out;

    const bool use_bias = ws_size >= (7 * AP + BT_ELEMS) * sizeof(float);
    const bool split4   = ws_size >= (7 * AP + BT_ELEMS + 4 * AP + 4 * PS_HALF) * sizeof(float);
    const bool split2   = ws_size >= (7 * AP + BT_ELEMS + 2 * AP + 2 * PS_HALF) * sizeof(float);

    prep_kernel<<<use_bias ? 5016 : 2112, 192, 0, stream>>>(x1, x2, qkv_w, qkv_b,
                                                            rpb, rel, ws, BT);
    fuse_kernel<<<dim3(H_HEADS, B_WIN), 256, 0, stream>>>(V1, V2, fuse_w, fuse_b, VF);
    if (use_bias && split4) {
        attn_part4<<<dim3(12, B_WIN, 4), 192, 0, stream>>>(ws, BT, VF, PA, PS4, 88, 11);
        proj_kernel<<<dim3(11, B_WIN), 192, 0, stream>>>(nullptr, PA, PS4, proj_w, proj_b, out, 4);
    } else if (use_bias && split2) {
        attn_part2<<<dim3(H_HEADS, B_WIN, 2), 192, 0, stream>>>(ws, BT, VF, PA, PS2);
        proj_kernel<<<dim3(11, B_WIN), 192, 0, stream>>>(nullptr, PA, PS2, proj_w, proj_b, out, 2);
    } else {
        if (use_bias)
            attn_full<<<dim3(H_HEADS, B_WIN), 192, 0, stream>>>(ws, BT, VF, AO);
        else
            attn_kernel_g<<<dim3(H_HEADS, B_WIN), 256, 0, stream>>>(ws, rpb, rel, VF, AO);
        proj_kernel<<<dim3(11, B_WIN), 192, 0, stream>>>(AO, nullptr, nullptr, proj_w, proj_b, out, 0);
    }
}